// Round 1
// baseline (350.904 us; speedup 1.0000x reference)
//
#include <hip/hip_runtime.h>

// ---------------- prep: fold W2e/W3 into per-node projections ----------------
// Wa[k][j] = sum_m W2e[k][m]      * W3[m][j]   (k<32, j<8)
// Wb[k][j] = sum_m W2e[32+k][m]   * W3[m][j]
// b3p[j]   = b3[j] + sum_m b2e[m] * W3[m][j]
__global__ void prep_kernel(const float* __restrict__ W2e, const float* __restrict__ b2e,
                            const float* __restrict__ W3,  const float* __restrict__ b3,
                            float* __restrict__ Wa, float* __restrict__ Wb,
                            float* __restrict__ b3p)
{
    int t = threadIdx.x;           // 256 threads
    int k = t >> 3, j = t & 7;
    float a = 0.f, b = 0.f;
    #pragma unroll
    for (int m = 0; m < 32; ++m) {
        float w3 = W3[m * 8 + j];
        a += W2e[k * 32 + m]        * w3;
        b += W2e[(32 + k) * 32 + m] * w3;
    }
    Wa[k * 8 + j] = a;
    Wb[k * 8 + j] = b;
    if (t < 8) {
        float s = b3[t];
        #pragma unroll
        for (int m = 0; m < 32; ++m) s += b2e[m] * W3[m * 8 + t];
        b3p[t] = s;
    }
}

// ---------------- per-node: emb gather/copy, cars1, A/B projections ----------
__global__ __launch_bounds__(256) void node_kernel(
    const int*   __restrict__ features,
    const float* __restrict__ cars,
    const float* __restrict__ entered,
    const float* __restrict__ embed_table,
    const float* __restrict__ W2n,   // 33
    const float* __restrict__ b2n,   // 1
    const float* __restrict__ W3,    // 35x8 (rows 32..34 used)
    const float* __restrict__ Wa,    // 32x8
    const float* __restrict__ Wb,    // 32x8
    float* __restrict__ emb_out,     // N x 32
    float* __restrict__ cars1,       // N
    float* __restrict__ A,           // N x 8
    float* __restrict__ B,           // N x 8
    int N)
{
    int i = blockIdx.x * blockDim.x + threadIdx.x;
    if (i >= N) return;
    int f = features[i];
    const float4* erow = (const float4*)(embed_table + (size_t)f * 32);
    float4* orow = (float4*)(emb_out + (size_t)i * 32);
    float e[32];
    #pragma unroll
    for (int q = 0; q < 8; ++q) {
        float4 v = erow[q];
        orow[q] = v;
        e[4*q+0] = v.x; e[4*q+1] = v.y; e[4*q+2] = v.z; e[4*q+3] = v.w;
    }
    float parked = b2n[0];
    #pragma unroll
    for (int k = 0; k < 32; ++k) parked += e[k] * W2n[k];
    float c = cars[i];
    parked += c * W2n[32];
    float c1 = fmaxf(fmaxf(parked, 0.f) + c, 0.f);
    cars1[i] = c1;

    float ent = entered[i];
    float a8[8], b8[8];
    #pragma unroll
    for (int j = 0; j < 8; ++j) {
        a8[j] = c1 * W3[32*8 + j] + ent * W3[34*8 + j];
        b8[j] = c1 * W3[33*8 + j];
    }
    #pragma unroll
    for (int k = 0; k < 32; ++k) {
        float x = e[k];
        #pragma unroll
        for (int j = 0; j < 8; ++j) {
            a8[j] += x * Wa[k*8 + j];
            b8[j] += x * Wb[k*8 + j];
        }
    }
    float4* Ar = (float4*)(A + (size_t)i * 8);
    float4* Br = (float4*)(B + (size_t)i * 8);
    Ar[0] = make_float4(a8[0], a8[1], a8[2], a8[3]);
    Ar[1] = make_float4(a8[4], a8[5], a8[6], a8[7]);
    Br[0] = make_float4(b8[0], b8[1], b8[2], b8[3]);
    Br[1] = make_float4(b8[4], b8[5], b8[6], b8[7]);
}

// ---------------- edge pass 1: logit + segment max (by src) ------------------
__global__ __launch_bounds__(256) void edge_logit_kernel(
    const int*   __restrict__ src, const int* __restrict__ dst,
    const int*   __restrict__ features,
    const float* __restrict__ free_,
    const float* __restrict__ A, const float* __restrict__ B,
    const float* __restrict__ b3p,
    const float* __restrict__ W4, const float* __restrict__ b4,
    float* __restrict__ l_out, float* __restrict__ mseg,
    int E)
{
    int e = blockIdx.x * blockDim.x + threadIdx.x;
    if (e >= E) return;
    int s = src[e], d = dst[e];
    const float4* As = (const float4*)(A + (size_t)s * 8);
    const float4* Bd = (const float4*)(B + (size_t)d * 8);
    float4 a0 = As[0], a1 = As[1], b0 = Bd[0], b1 = Bd[1];
    float h[8] = { a0.x + b0.x, a0.y + b0.y, a0.z + b0.z, a0.w + b0.w,
                   a1.x + b1.x, a1.y + b1.y, a1.z + b1.z, a1.w + b1.w };
    float out = b4[0];
    #pragma unroll
    for (int j = 0; j < 8; ++j) out += fmaxf(h[j] + b3p[j], 0.f) * W4[j];
    float selfloop = (features[s] == features[d]) ? 1.f : 0.f;
    float enabled  = (selfloop != free_[s]) ? 1.f : 0.f;
    float l = fmaxf(out, 0.f) * enabled;           // l >= 0 always
    l_out[e] = l;
    // non-negative floats compare correctly as unsigned ints
    atomicMax((unsigned int*)(mseg + s), __float_as_uint(l));
}

// ---------------- edge pass 2: exp + segment sum (by src) --------------------
__global__ __launch_bounds__(256) void edge_exp_kernel(
    const int* __restrict__ src,
    const float* __restrict__ mseg,
    float* __restrict__ lex,      // in: l, out: exp(l - m[src])
    float* __restrict__ ssum,
    int E)
{
    int e = blockIdx.x * blockDim.x + threadIdx.x;
    if (e >= E) return;
    int s = src[e];
    float ex = expf(lex[e] - mseg[s]);
    lex[e] = ex;
    atomicAdd(ssum + s, ex);
}

// ---------------- edge pass 3: prob + scatter to dst -------------------------
__global__ __launch_bounds__(256) void edge_scatter_kernel(
    const int* __restrict__ src, const int* __restrict__ dst,
    const int* __restrict__ features,
    const float* __restrict__ cars1,
    const float* __restrict__ lex, const float* __restrict__ ssum,
    float* __restrict__ cars_out, float* __restrict__ entered_out,
    int E)
{
    int e = blockIdx.x * blockDim.x + threadIdx.x;
    if (e >= E) return;
    int s = src[e], d = dst[e];
    float prob = lex[e] / ssum[s];
    float c = cars1[s] * prob;
    float selfloop = (features[s] == features[d]) ? 1.f : 0.f;
    atomicAdd(cars_out + d, c);
    atomicAdd(entered_out + d, c * (1.f - selfloop));
}

extern "C" void kernel_launch(void* const* d_in, const int* in_sizes, int n_in,
                              void* d_out, int out_size, void* d_ws, size_t ws_size,
                              hipStream_t stream)
{
    const int N = in_sizes[0];     // 100000
    const int E = in_sizes[4];     // 1600000

    const int*   features    = (const int*)  d_in[0];
    const float* cars        = (const float*)d_in[1];
    const float* entered     = (const float*)d_in[2];
    const float* free_       = (const float*)d_in[3];
    const int*   src         = (const int*)  d_in[4];
    const int*   dst         = (const int*)  d_in[5];
    const float* embed_table = (const float*)d_in[6];
    const float* W2n         = (const float*)d_in[7];
    const float* b2n         = (const float*)d_in[8];
    const float* W2e         = (const float*)d_in[9];
    const float* b2e         = (const float*)d_in[10];
    const float* W3          = (const float*)d_in[11];
    const float* b3          = (const float*)d_in[12];
    const float* W4          = (const float*)d_in[13];
    const float* b4          = (const float*)d_in[14];

    float* out         = (float*)d_out;
    float* cars_out    = out;                       // N
    float* emb_out     = out + N;                   // N*32
    float* entered_out = out + (size_t)N * 33;      // N

    // workspace layout (floats)
    float* ws    = (float*)d_ws;
    float* Wa    = ws;                      // 256
    float* Wb    = ws + 256;                // 256
    float* b3p   = ws + 512;                // 8 (pad to 16)
    float* cars1 = ws + 528;                // N
    float* A     = cars1 + N;               // N*8
    float* B     = A + (size_t)N * 8;       // N*8
    float* mseg  = B + (size_t)N * 8;       // N
    float* ssum  = mseg + N;                // N
    float* lex   = ssum + N;                // E

    hipMemsetAsync(cars_out,    0, (size_t)N * sizeof(float), stream);
    hipMemsetAsync(entered_out, 0, (size_t)N * sizeof(float), stream);
    hipMemsetAsync(mseg,        0, (size_t)2 * N * sizeof(float), stream); // mseg + ssum

    prep_kernel<<<1, 256, 0, stream>>>(W2e, b2e, W3, b3, Wa, Wb, b3p);
    node_kernel<<<(N + 255) / 256, 256, 0, stream>>>(
        features, cars, entered, embed_table, W2n, b2n, W3, Wa, Wb,
        emb_out, cars1, A, B, N);

    int eg = (E + 255) / 256;
    edge_logit_kernel<<<eg, 256, 0, stream>>>(
        src, dst, features, free_, A, B, b3p, W4, b4, lex, mseg, E);
    edge_exp_kernel<<<eg, 256, 0, stream>>>(src, mseg, lex, ssum, E);
    edge_scatter_kernel<<<eg, 256, 0, stream>>>(
        src, dst, features, cars1, lex, ssum, cars_out, entered_out, E);
}

// Round 2
// 272.967 us; speedup vs baseline: 1.2855x; 1.2855x over previous
//
#include <hip/hip_runtime.h>

// ---------------- prep: fold W2e/W3 into per-node projections ----------------
// Wa[k][j] = sum_m W2e[k][m]    * W3[m][j]   (k<32, j<8)
// Wb[k][j] = sum_m W2e[32+k][m] * W3[m][j]
// b3p[j]   = b3[j] + sum_m b2e[m] * W3[m][j]
__global__ void prep_kernel(const float* __restrict__ W2e, const float* __restrict__ b2e,
                            const float* __restrict__ W3,  const float* __restrict__ b3,
                            float* __restrict__ Wa, float* __restrict__ Wb,
                            float* __restrict__ b3p)
{
    int t = threadIdx.x;           // 256 threads
    int k = t >> 3, j = t & 7;
    float a = 0.f, b = 0.f;
    #pragma unroll
    for (int m = 0; m < 32; ++m) {
        float w3 = W3[m * 8 + j];
        a += W2e[k * 32 + m]        * w3;
        b += W2e[(32 + k) * 32 + m] * w3;
    }
    Wa[k * 8 + j] = a;
    Wb[k * 8 + j] = b;
    if (t < 8) {
        float s = b3[t];
        #pragma unroll
        for (int m = 0; m < 32; ++m) s += b2e[m] * W3[m * 8 + t];
        b3p[t] = s;
    }
}

// ---------------- per-node: emb gather/copy, cars1, A/B projections ----------
// Also zeroes ssum / cars_out / entered_out (replaces memsets) and packs
// sfree[i] = { (float)feature, free } for the edge pass.
__global__ __launch_bounds__(256) void node_kernel(
    const int*   __restrict__ features,
    const float* __restrict__ cars,
    const float* __restrict__ entered,
    const float* __restrict__ free_,
    const float* __restrict__ embed_table,
    const float* __restrict__ W2n,   // 33
    const float* __restrict__ b2n,   // 1
    const float* __restrict__ W3,    // 35x8 (rows 32..34 used)
    const float* __restrict__ Wa,    // 32x8
    const float* __restrict__ Wb,    // 32x8
    float* __restrict__ emb_out,     // N x 32
    float* __restrict__ cars1,       // N
    float* __restrict__ A,           // N x 8
    float* __restrict__ B,           // N x 8
    float2* __restrict__ sfree,      // N
    float* __restrict__ ssum,        // N (zeroed here)
    float* __restrict__ cars_out,    // N (zeroed here)
    float* __restrict__ entered_out, // N (zeroed here)
    int N)
{
    int i = blockIdx.x * blockDim.x + threadIdx.x;
    if (i >= N) return;
    int f = features[i];
    const float4* erow = (const float4*)(embed_table + (size_t)f * 32);
    float4* orow = (float4*)(emb_out + (size_t)i * 32);
    float e[32];
    #pragma unroll
    for (int q = 0; q < 8; ++q) {
        float4 v = erow[q];
        orow[q] = v;
        e[4*q+0] = v.x; e[4*q+1] = v.y; e[4*q+2] = v.z; e[4*q+3] = v.w;
    }
    float parked = b2n[0];
    #pragma unroll
    for (int k = 0; k < 32; ++k) parked += e[k] * W2n[k];
    float c = cars[i];
    parked += c * W2n[32];
    float c1 = fmaxf(fmaxf(parked, 0.f) + c, 0.f);
    cars1[i] = c1;
    sfree[i] = make_float2((float)f, free_[i]);   // features < 2^24: exact in f32
    ssum[i] = 0.f;
    cars_out[i] = 0.f;
    entered_out[i] = 0.f;

    float ent = entered[i];
    float a8[8], b8[8];
    #pragma unroll
    for (int j = 0; j < 8; ++j) {
        a8[j] = c1 * W3[32*8 + j] + ent * W3[34*8 + j];
        b8[j] = c1 * W3[33*8 + j];
    }
    #pragma unroll
    for (int k = 0; k < 32; ++k) {
        float x = e[k];
        #pragma unroll
        for (int j = 0; j < 8; ++j) {
            a8[j] += x * Wa[k*8 + j];
            b8[j] += x * Wb[k*8 + j];
        }
    }
    float4* Ar = (float4*)(A + (size_t)i * 8);
    float4* Br = (float4*)(B + (size_t)i * 8);
    Ar[0] = make_float4(a8[0], a8[1], a8[2], a8[3]);
    Ar[1] = make_float4(a8[4], a8[5], a8[6], a8[7]);
    Br[0] = make_float4(b8[0], b8[1], b8[2], b8[3]);
    Br[1] = make_float4(b8[4], b8[5], b8[6], b8[7]);
}

// -------- edge pass 1: logit, exp (no max needed: l is O(1)), segment sum ----
// Stores ex sign-encoded: negative iff selfloop. ex = exp(l) >= 1 > 0 always.
__global__ __launch_bounds__(256) void edge_pass1_kernel(
    const int*   __restrict__ src, const int* __restrict__ dst,
    const float2* __restrict__ sfree,
    const float* __restrict__ A, const float* __restrict__ B,
    const float* __restrict__ b3p,
    const float* __restrict__ W4, const float* __restrict__ b4,
    float* __restrict__ lex, float* __restrict__ ssum,
    int E)
{
    int e = blockIdx.x * blockDim.x + threadIdx.x;
    if (e >= E) return;
    int s = src[e], d = dst[e];
    const float4* As = (const float4*)(A + (size_t)s * 8);
    const float4* Bd = (const float4*)(B + (size_t)d * 8);
    float4 a0 = As[0], a1 = As[1], b0 = Bd[0], b1 = Bd[1];
    float2 fs = sfree[s];
    float  fd = sfree[d].x;
    float h[8] = { a0.x + b0.x, a0.y + b0.y, a0.z + b0.z, a0.w + b0.w,
                   a1.x + b1.x, a1.y + b1.y, a1.z + b1.z, a1.w + b1.w };
    float out = b4[0];
    #pragma unroll
    for (int j = 0; j < 8; ++j) out += fmaxf(h[j] + b3p[j], 0.f) * W4[j];
    bool selfloop = (fs.x == fd);
    float slf = selfloop ? 1.f : 0.f;
    float enabled = (slf != fs.y) ? 1.f : 0.f;
    float l = fmaxf(out, 0.f) * enabled;
    float ex = __expf(l);                    // l in [0, ~10] — no overflow
    lex[e] = selfloop ? -ex : ex;
    unsafeAtomicAdd(ssum + s, ex);           // native global_atomic_add_f32
}

// ---------------- ratio: cars1 / ssum per node -------------------------------
__global__ __launch_bounds__(256) void ratio_kernel(
    const float* __restrict__ cars1, const float* __restrict__ ssum,
    float* __restrict__ ratio, int N)
{
    int i = blockIdx.x * blockDim.x + threadIdx.x;
    if (i >= N) return;
    ratio[i] = cars1[i] / ssum[i];   // nodes with no out-edges: value unused
}

// ---------------- edge pass 2: scatter to dst --------------------------------
__global__ __launch_bounds__(256) void edge_pass2_kernel(
    const int* __restrict__ src, const int* __restrict__ dst,
    const float* __restrict__ lex, const float* __restrict__ ratio,
    float* __restrict__ cars_out, float* __restrict__ entered_out,
    int E)
{
    int e = blockIdx.x * blockDim.x + threadIdx.x;
    if (e >= E) return;
    int s = src[e], d = dst[e];
    float lv = lex[e];
    float ex = fabsf(lv);
    float c = ratio[s] * ex;
    unsafeAtomicAdd(cars_out + d, c);
    float ent = (lv < 0.f) ? 0.f : c;        // selfloop -> no entered contribution
    unsafeAtomicAdd(entered_out + d, ent);
}

extern "C" void kernel_launch(void* const* d_in, const int* in_sizes, int n_in,
                              void* d_out, int out_size, void* d_ws, size_t ws_size,
                              hipStream_t stream)
{
    const int N = in_sizes[0];     // 100000
    const int E = in_sizes[4];     // 1600000

    const int*   features    = (const int*)  d_in[0];
    const float* cars        = (const float*)d_in[1];
    const float* entered     = (const float*)d_in[2];
    const float* free_       = (const float*)d_in[3];
    const int*   src         = (const int*)  d_in[4];
    const int*   dst         = (const int*)  d_in[5];
    const float* embed_table = (const float*)d_in[6];
    const float* W2n         = (const float*)d_in[7];
    const float* b2n         = (const float*)d_in[8];
    const float* W2e         = (const float*)d_in[9];
    const float* b2e         = (const float*)d_in[10];
    const float* W3          = (const float*)d_in[11];
    const float* b3          = (const float*)d_in[12];
    const float* W4          = (const float*)d_in[13];
    const float* b4          = (const float*)d_in[14];

    float* out         = (float*)d_out;
    float* cars_out    = out;                       // N
    float* emb_out     = out + N;                   // N*32
    float* entered_out = out + (size_t)N * 33;      // N

    // workspace layout (floats)
    float*  ws    = (float*)d_ws;
    float*  Wa    = ws;                       // 256
    float*  Wb    = ws + 256;                 // 256
    float*  b3p   = ws + 512;                 // 16 (8 used)
    float2* sfree = (float2*)(ws + 528);      // N float2 (8B-aligned)
    float*  cars1 = ws + 528 + (size_t)2 * N; // N
    float*  A     = cars1 + N;                // N*8 (16B-aligned)
    float*  B     = A + (size_t)N * 8;        // N*8
    float*  ssum  = B + (size_t)N * 8;        // N
    float*  ratio = ssum + N;                 // N
    float*  lex   = ratio + N;                // E

    prep_kernel<<<1, 256, 0, stream>>>(W2e, b2e, W3, b3, Wa, Wb, b3p);
    node_kernel<<<(N + 255) / 256, 256, 0, stream>>>(
        features, cars, entered, free_, embed_table, W2n, b2n, W3, Wa, Wb,
        emb_out, cars1, A, B, sfree, ssum, cars_out, entered_out, N);

    int eg = (E + 255) / 256;
    edge_pass1_kernel<<<eg, 256, 0, stream>>>(
        src, dst, sfree, A, B, b3p, W4, b4, lex, ssum, E);
    ratio_kernel<<<(N + 255) / 256, 256, 0, stream>>>(cars1, ssum, ratio, N);
    edge_pass2_kernel<<<eg, 256, 0, stream>>>(
        src, dst, lex, ratio, cars_out, entered_out, E);
}

// Round 3
// 200.259 us; speedup vs baseline: 1.7523x; 1.3631x over previous
//
#include <hip/hip_runtime.h>

// ---------------- prep: fold W2e/W3 into per-node projections ----------------
// Wa[k][j] = sum_m W2e[k][m]    * W3[m][j]   (k<32, j<8)
// Wb[k][j] = sum_m W2e[32+k][m] * W3[m][j]
// b3p[j]   = b3[j] + sum_m b2e[m] * W3[m][j]
__global__ void prep_kernel(const float* __restrict__ W2e, const float* __restrict__ b2e,
                            const float* __restrict__ W3,  const float* __restrict__ b3,
                            float* __restrict__ Wa, float* __restrict__ Wb,
                            float* __restrict__ b3p)
{
    int t = threadIdx.x;           // 256 threads
    int k = t >> 3, j = t & 7;
    float a = 0.f, b = 0.f;
    #pragma unroll
    for (int m = 0; m < 32; ++m) {
        float w3 = W3[m * 8 + j];
        a += W2e[k * 32 + m]        * w3;
        b += W2e[(32 + k) * 32 + m] * w3;
    }
    Wa[k * 8 + j] = a;
    Wb[k * 8 + j] = b;
    if (t < 8) {
        float s = b3[t];
        #pragma unroll
        for (int m = 0; m < 32; ++m) s += b2e[m] * W3[m * 8 + t];
        b3p[t] = s;
    }
}

// ---------------- per-node: emb gather/copy, cars1, A/B projections ----------
// Also zeroes ssum / cars_out / entered_out (entered_out doubles as the
// selfloop-delta accumulator during edge pass 2).
__global__ __launch_bounds__(256) void node_kernel(
    const int*   __restrict__ features,
    const float* __restrict__ cars,
    const float* __restrict__ entered,
    const float* __restrict__ free_,
    const float* __restrict__ embed_table,
    const float* __restrict__ W2n,   // 33
    const float* __restrict__ b2n,   // 1
    const float* __restrict__ W3,    // 35x8 (rows 32..34 used)
    const float* __restrict__ Wa,    // 32x8
    const float* __restrict__ Wb,    // 32x8
    float* __restrict__ emb_out,     // N x 32
    float* __restrict__ cars1,       // N
    float* __restrict__ A,           // N x 8
    float* __restrict__ B,           // N x 8
    float2* __restrict__ sfree,      // N
    float* __restrict__ ssum,        // N (zeroed here)
    float* __restrict__ cars_out,    // N (zeroed here)
    float* __restrict__ entered_out, // N (zeroed here; used as delta acc)
    int N)
{
    int i = blockIdx.x * blockDim.x + threadIdx.x;
    if (i >= N) return;
    int f = features[i];
    const float4* erow = (const float4*)(embed_table + (size_t)f * 32);
    float4* orow = (float4*)(emb_out + (size_t)i * 32);
    float e[32];
    #pragma unroll
    for (int q = 0; q < 8; ++q) {
        float4 v = erow[q];
        orow[q] = v;
        e[4*q+0] = v.x; e[4*q+1] = v.y; e[4*q+2] = v.z; e[4*q+3] = v.w;
    }
    float parked = b2n[0];
    #pragma unroll
    for (int k = 0; k < 32; ++k) parked += e[k] * W2n[k];
    float c = cars[i];
    parked += c * W2n[32];
    float c1 = fmaxf(fmaxf(parked, 0.f) + c, 0.f);
    cars1[i] = c1;
    sfree[i] = make_float2((float)f, free_[i]);   // features < 2^24: exact in f32
    ssum[i] = 0.f;
    cars_out[i] = 0.f;
    entered_out[i] = 0.f;

    float ent = entered[i];
    float a8[8], b8[8];
    #pragma unroll
    for (int j = 0; j < 8; ++j) {
        a8[j] = c1 * W3[32*8 + j] + ent * W3[34*8 + j];
        b8[j] = c1 * W3[33*8 + j];
    }
    #pragma unroll
    for (int k = 0; k < 32; ++k) {
        float x = e[k];
        #pragma unroll
        for (int j = 0; j < 8; ++j) {
            a8[j] += x * Wa[k*8 + j];
            b8[j] += x * Wb[k*8 + j];
        }
    }
    float4* Ar = (float4*)(A + (size_t)i * 8);
    float4* Br = (float4*)(B + (size_t)i * 8);
    Ar[0] = make_float4(a8[0], a8[1], a8[2], a8[3]);
    Ar[1] = make_float4(a8[4], a8[5], a8[6], a8[7]);
    Br[0] = make_float4(b8[0], b8[1], b8[2], b8[3]);
    Br[1] = make_float4(b8[4], b8[5], b8[6], b8[7]);
}

// -------- edge pass 1: logit, exp (no max needed: l is O(1)), segment sum ----
// Stores ex sign-encoded: negative iff selfloop. ex = exp(l) >= 1 > 0 always.
__global__ __launch_bounds__(256) void edge_pass1_kernel(
    const int*   __restrict__ src, const int* __restrict__ dst,
    const float2* __restrict__ sfree,
    const float* __restrict__ A, const float* __restrict__ B,
    const float* __restrict__ b3p,
    const float* __restrict__ W4, const float* __restrict__ b4,
    float* __restrict__ lex, float* __restrict__ ssum,
    int E)
{
    int e = blockIdx.x * blockDim.x + threadIdx.x;
    if (e >= E) return;
    int s = src[e], d = dst[e];
    const float4* As = (const float4*)(A + (size_t)s * 8);
    const float4* Bd = (const float4*)(B + (size_t)d * 8);
    float4 a0 = As[0], a1 = As[1], b0 = Bd[0], b1 = Bd[1];
    float2 fs = sfree[s];
    float  fd = sfree[d].x;
    float h[8] = { a0.x + b0.x, a0.y + b0.y, a0.z + b0.z, a0.w + b0.w,
                   a1.x + b1.x, a1.y + b1.y, a1.z + b1.z, a1.w + b1.w };
    float out = b4[0];
    #pragma unroll
    for (int j = 0; j < 8; ++j) out += fmaxf(h[j] + b3p[j], 0.f) * W4[j];
    bool selfloop = (fs.x == fd);
    float slf = selfloop ? 1.f : 0.f;
    float enabled = (slf != fs.y) ? 1.f : 0.f;
    float l = fmaxf(out, 0.f) * enabled;
    float ex = __expf(l);                    // l in [0, ~10] — no overflow
    lex[e] = selfloop ? -ex : ex;
    unsafeAtomicAdd(ssum + s, ex);           // native global_atomic_add_f32
}

// ---------------- ratio: cars1 / ssum per node -------------------------------
__global__ __launch_bounds__(256) void ratio_kernel(
    const float* __restrict__ cars1, const float* __restrict__ ssum,
    float* __restrict__ ratio, int N)
{
    int i = blockIdx.x * blockDim.x + threadIdx.x;
    if (i >= N) return;
    ratio[i] = cars1[i] / ssum[i];   // nodes with no out-edges: value unused
}

// ---------------- edge pass 2: scatter to dst --------------------------------
// cars_out  += c for every edge (1 atomic/edge).
// entered_out (as delta) += c ONLY for selfloop edges (rare).
// Final: entered_out = cars_out - delta  (fixup kernel).
__global__ __launch_bounds__(256) void edge_pass2_kernel(
    const int* __restrict__ src, const int* __restrict__ dst,
    const float* __restrict__ lex, const float* __restrict__ ratio,
    float* __restrict__ cars_out, float* __restrict__ delta,
    int E)
{
    int e = blockIdx.x * blockDim.x + threadIdx.x;
    if (e >= E) return;
    int s = src[e], d = dst[e];
    float lv = lex[e];
    float ex = fabsf(lv);
    float c = ratio[s] * ex;
    unsafeAtomicAdd(cars_out + d, c);
    if (lv < 0.f)                            // selfloop: entered misses this c
        unsafeAtomicAdd(delta + d, c);
}

// ---------------- fixup: entered_out = cars_out - delta ----------------------
__global__ __launch_bounds__(256) void fixup_kernel(
    const float* __restrict__ cars_out, float* __restrict__ entered_out, int N)
{
    int i = blockIdx.x * blockDim.x + threadIdx.x;
    if (i >= N) return;
    entered_out[i] = cars_out[i] - entered_out[i];
}

extern "C" void kernel_launch(void* const* d_in, const int* in_sizes, int n_in,
                              void* d_out, int out_size, void* d_ws, size_t ws_size,
                              hipStream_t stream)
{
    const int N = in_sizes[0];     // 100000
    const int E = in_sizes[4];     // 1600000

    const int*   features    = (const int*)  d_in[0];
    const float* cars        = (const float*)d_in[1];
    const float* entered     = (const float*)d_in[2];
    const float* free_       = (const float*)d_in[3];
    const int*   src         = (const int*)  d_in[4];
    const int*   dst         = (const int*)  d_in[5];
    const float* embed_table = (const float*)d_in[6];
    const float* W2n         = (const float*)d_in[7];
    const float* b2n         = (const float*)d_in[8];
    const float* W2e         = (const float*)d_in[9];
    const float* b2e         = (const float*)d_in[10];
    const float* W3          = (const float*)d_in[11];
    const float* b3          = (const float*)d_in[12];
    const float* W4          = (const float*)d_in[13];
    const float* b4          = (const float*)d_in[14];

    float* out         = (float*)d_out;
    float* cars_out    = out;                       // N
    float* emb_out     = out + N;                   // N*32
    float* entered_out = out + (size_t)N * 33;      // N

    // workspace layout (floats)
    float*  ws    = (float*)d_ws;
    float*  Wa    = ws;                       // 256
    float*  Wb    = ws + 256;                 // 256
    float*  b3p   = ws + 512;                 // 16 (8 used)
    float2* sfree = (float2*)(ws + 528);      // N float2 (8B-aligned)
    float*  cars1 = ws + 528 + (size_t)2 * N; // N
    float*  A     = cars1 + N;                // N*8 (16B-aligned)
    float*  B     = A + (size_t)N * 8;        // N*8
    float*  ssum  = B + (size_t)N * 8;        // N
    float*  ratio = ssum + N;                 // N
    float*  lex   = ratio + N;                // E

    prep_kernel<<<1, 256, 0, stream>>>(W2e, b2e, W3, b3, Wa, Wb, b3p);
    node_kernel<<<(N + 255) / 256, 256, 0, stream>>>(
        features, cars, entered, free_, embed_table, W2n, b2n, W3, Wa, Wb,
        emb_out, cars1, A, B, sfree, ssum, cars_out, entered_out, N);

    int eg = (E + 255) / 256;
    edge_pass1_kernel<<<eg, 256, 0, stream>>>(
        src, dst, sfree, A, B, b3p, W4, b4, lex, ssum, E);
    ratio_kernel<<<(N + 255) / 256, 256, 0, stream>>>(cars1, ssum, ratio, N);
    edge_pass2_kernel<<<eg, 256, 0, stream>>>(
        src, dst, lex, ratio, cars_out, entered_out, E);
    fixup_kernel<<<(N + 255) / 256, 256, 0, stream>>>(cars_out, entered_out, N);
}

// Round 4
// 190.362 us; speedup vs baseline: 1.8433x; 1.0520x over previous
//
#include <hip/hip_runtime.h>

typedef _Float16 f16x8 __attribute__((ext_vector_type(8)));

#define NXCD 8

__device__ __forceinline__ int xcc_id() {
    int x;
    asm("s_getreg_b32 %0, hwreg(HW_REG_XCC_ID)" : "=s"(x));
    return x & (NXCD - 1);
}

// Workgroup-scope fp atomic: lowers to global_atomic_add_f32 WITHOUT the
// device-coherence bit -> executes in the local XCD's L2, no fabric
// write-through. Safe because each XCD gets its own partial array.
__device__ __forceinline__ void l2AtomicAdd(float* p, float v) {
    __hip_atomic_fetch_add(p, v, __ATOMIC_RELAXED, __HIP_MEMORY_SCOPE_WORKGROUP);
}

// ---------------- prep: fold W2e/W3 into per-node projections ----------------
__global__ void prep_kernel(const float* __restrict__ W2e, const float* __restrict__ b2e,
                            const float* __restrict__ W3,  const float* __restrict__ b3,
                            float* __restrict__ Wa, float* __restrict__ Wb,
                            float* __restrict__ b3p)
{
    int t = threadIdx.x;           // 256 threads
    int k = t >> 3, j = t & 7;
    float a = 0.f, b = 0.f;
    #pragma unroll
    for (int m = 0; m < 32; ++m) {
        float w3 = W3[m * 8 + j];
        a += W2e[k * 32 + m]        * w3;
        b += W2e[(32 + k) * 32 + m] * w3;
    }
    Wa[k * 8 + j] = a;
    Wb[k * 8 + j] = b;
    if (t < 8) {
        float s = b3[t];
        #pragma unroll
        for (int m = 0; m < 32; ++m) s += b2e[m] * W3[m * 8 + t];
        b3p[t] = s;
    }
}

// ---------------- per-node: emb gather/copy, cars1, A/B (f16) ----------------
// Also zeroes the per-XCD partial arrays and entered_out (delta accumulator).
__global__ __launch_bounds__(256) void node_kernel(
    const int*   __restrict__ features,
    const float* __restrict__ cars,
    const float* __restrict__ entered,
    const float* __restrict__ free_,
    const float* __restrict__ embed_table,
    const float* __restrict__ W2n,   // 33
    const float* __restrict__ b2n,   // 1
    const float* __restrict__ W3,    // 35x8 (rows 32..34 used)
    const float* __restrict__ Wa,    // 32x8
    const float* __restrict__ Wb,    // 32x8
    float* __restrict__ emb_out,     // N x 32
    float* __restrict__ cars1,       // N
    f16x8* __restrict__ Ah,          // N
    f16x8* __restrict__ Bh,          // N
    float2* __restrict__ sfree,      // N
    float* __restrict__ ssum_part,   // 8N (zeroed here)
    float* __restrict__ cars_part,   // 8N (zeroed here)
    float* __restrict__ entered_out, // N (zeroed here; delta accumulator)
    int N)
{
    int i = blockIdx.x * blockDim.x + threadIdx.x;
    if (i >= N) return;
    int f = features[i];
    const float4* erow = (const float4*)(embed_table + (size_t)f * 32);
    float4* orow = (float4*)(emb_out + (size_t)i * 32);
    float e[32];
    #pragma unroll
    for (int q = 0; q < 8; ++q) {
        float4 v = erow[q];
        orow[q] = v;
        e[4*q+0] = v.x; e[4*q+1] = v.y; e[4*q+2] = v.z; e[4*q+3] = v.w;
    }
    float parked = b2n[0];
    #pragma unroll
    for (int k = 0; k < 32; ++k) parked += e[k] * W2n[k];
    float c = cars[i];
    parked += c * W2n[32];
    float c1 = fmaxf(fmaxf(parked, 0.f) + c, 0.f);
    cars1[i] = c1;
    sfree[i] = make_float2((float)f, free_[i]);   // features < 2^24: exact in f32
    entered_out[i] = 0.f;
    #pragma unroll
    for (int x = 0; x < NXCD; ++x) {
        ssum_part[(size_t)x * N + i] = 0.f;
        cars_part[(size_t)x * N + i] = 0.f;
    }

    float ent = entered[i];
    float a8[8], b8[8];
    #pragma unroll
    for (int j = 0; j < 8; ++j) {
        a8[j] = c1 * W3[32*8 + j] + ent * W3[34*8 + j];
        b8[j] = c1 * W3[33*8 + j];
    }
    #pragma unroll
    for (int k = 0; k < 32; ++k) {
        float x = e[k];
        #pragma unroll
        for (int j = 0; j < 8; ++j) {
            a8[j] += x * Wa[k*8 + j];
            b8[j] += x * Wb[k*8 + j];
        }
    }
    f16x8 av, bv;
    #pragma unroll
    for (int j = 0; j < 8; ++j) { av[j] = (_Float16)a8[j]; bv[j] = (_Float16)b8[j]; }
    Ah[i] = av;
    Bh[i] = bv;
}

// -------- edge pass 1: logit, exp (no max: l is O(1)), L2-local segment sum --
// Stores ex sign-encoded in f16: negative iff selfloop. ex >= 1 always.
__global__ __launch_bounds__(256) void edge_pass1_kernel(
    const int*   __restrict__ src, const int* __restrict__ dst,
    const float2* __restrict__ sfree,
    const f16x8* __restrict__ Ah, const f16x8* __restrict__ Bh,
    const float* __restrict__ b3p,
    const float* __restrict__ W4, const float* __restrict__ b4,
    _Float16* __restrict__ lexh, float* __restrict__ ssum_part,
    int E, int N)
{
    int e = blockIdx.x * blockDim.x + threadIdx.x;
    if (e >= E) return;
    int s = src[e], d = dst[e];
    f16x8 av = Ah[s];
    f16x8 bv = Bh[d];
    float2 fs = sfree[s];
    float  fd = sfree[d].x;
    float out = b4[0];
    #pragma unroll
    for (int j = 0; j < 8; ++j)
        out += fmaxf((float)av[j] + (float)bv[j] + b3p[j], 0.f) * W4[j];
    bool selfloop = (fs.x == fd);
    float slf = selfloop ? 1.f : 0.f;
    float enabled = (slf != fs.y) ? 1.f : 0.f;
    float l = fmaxf(out, 0.f) * enabled;
    float ex = __expf(l);                    // l in [0, ~6] — no overflow
    lexh[e] = (_Float16)(selfloop ? -ex : ex);
    l2AtomicAdd(ssum_part + (size_t)xcc_id() * N + s, ex);
}

// ---------------- ratio: cars1 / sum(ssum partials) --------------------------
__global__ __launch_bounds__(256) void ratio_kernel(
    const float* __restrict__ cars1, const float* __restrict__ ssum_part,
    float* __restrict__ ratio, int N)
{
    int i = blockIdx.x * blockDim.x + threadIdx.x;
    if (i >= N) return;
    float s = 0.f;
    #pragma unroll
    for (int x = 0; x < NXCD; ++x) s += ssum_part[(size_t)x * N + i];
    ratio[i] = cars1[i] / s;   // nodes with no out-edges: value unused
}

// ---------------- edge pass 2: scatter to dst (L2-local) ---------------------
__global__ __launch_bounds__(256) void edge_pass2_kernel(
    const int* __restrict__ src, const int* __restrict__ dst,
    const _Float16* __restrict__ lexh, const float* __restrict__ ratio,
    float* __restrict__ cars_part, float* __restrict__ delta,
    int E, int N)
{
    int e = blockIdx.x * blockDim.x + threadIdx.x;
    if (e >= E) return;
    int s = src[e], d = dst[e];
    float lv = (float)lexh[e];
    float ex = fabsf(lv);
    float c = ratio[s] * ex;
    l2AtomicAdd(cars_part + (size_t)xcc_id() * N + d, c);
    if (lv < 0.f)                 // selfloop: rare (~E/VOCAB edges) -> device scope ok
        unsafeAtomicAdd(delta + d, c);
}

// ------------- fixup: cars_out = sum(partials); entered = cars - delta -------
__global__ __launch_bounds__(256) void fixup_kernel(
    const float* __restrict__ cars_part,
    float* __restrict__ cars_out, float* __restrict__ entered_out, int N)
{
    int i = blockIdx.x * blockDim.x + threadIdx.x;
    if (i >= N) return;
    float cs = 0.f;
    #pragma unroll
    for (int x = 0; x < NXCD; ++x) cs += cars_part[(size_t)x * N + i];
    cars_out[i] = cs;
    entered_out[i] = cs - entered_out[i];   // entered_out held selfloop delta
}

extern "C" void kernel_launch(void* const* d_in, const int* in_sizes, int n_in,
                              void* d_out, int out_size, void* d_ws, size_t ws_size,
                              hipStream_t stream)
{
    const int N = in_sizes[0];     // 100000
    const int E = in_sizes[4];     // 1600000

    const int*   features    = (const int*)  d_in[0];
    const float* cars        = (const float*)d_in[1];
    const float* entered     = (const float*)d_in[2];
    const float* free_       = (const float*)d_in[3];
    const int*   src         = (const int*)  d_in[4];
    const int*   dst         = (const int*)  d_in[5];
    const float* embed_table = (const float*)d_in[6];
    const float* W2n         = (const float*)d_in[7];
    const float* b2n         = (const float*)d_in[8];
    const float* W2e         = (const float*)d_in[9];
    const float* b2e         = (const float*)d_in[10];
    const float* W3          = (const float*)d_in[11];
    const float* b3          = (const float*)d_in[12];
    const float* W4          = (const float*)d_in[13];
    const float* b4          = (const float*)d_in[14];

    float* out         = (float*)d_out;
    float* cars_out    = out;                       // N
    float* emb_out     = out + N;                   // N*32
    float* entered_out = out + (size_t)N * 33;      // N

    // workspace layout (float offsets; alignment: sfree 8B, Ah/Bh 16B ok)
    float*    ws        = (float*)d_ws;
    float*    Wa        = ws;                         // 256
    float*    Wb        = ws + 256;                   // 256
    float*    b3p       = ws + 512;                   // 16 (8 used)
    float*    cars1     = ws + 528;                   // N
    float*    ratio     = cars1 + N;                  // N
    float2*   sfree     = (float2*)(ws + 528 + (size_t)2 * N);  // N float2
    f16x8*    Ah        = (f16x8*)(ws + 528 + (size_t)4 * N);   // N * 16B
    f16x8*    Bh        = (f16x8*)(ws + 528 + (size_t)8 * N);   // N * 16B
    float*    ssum_part = ws + 528 + (size_t)12 * N;  // 8N
    float*    cars_part = ws + 528 + (size_t)20 * N;  // 8N
    _Float16* lexh      = (_Float16*)(ws + 528 + (size_t)28 * N); // E halves

    prep_kernel<<<1, 256, 0, stream>>>(W2e, b2e, W3, b3, Wa, Wb, b3p);
    node_kernel<<<(N + 255) / 256, 256, 0, stream>>>(
        features, cars, entered, free_, embed_table, W2n, b2n, W3, Wa, Wb,
        emb_out, cars1, Ah, Bh, sfree, ssum_part, cars_part, entered_out, N);

    int eg = (E + 255) / 256;
    edge_pass1_kernel<<<eg, 256, 0, stream>>>(
        src, dst, sfree, Ah, Bh, b3p, W4, b4, lexh, ssum_part, E, N);
    ratio_kernel<<<(N + 255) / 256, 256, 0, stream>>>(cars1, ssum_part, ratio, N);
    edge_pass2_kernel<<<eg, 256, 0, stream>>>(
        src, dst, lexh, ratio, cars_part, entered_out, E, N);
    fixup_kernel<<<(N + 255) / 256, 256, 0, stream>>>(
        cars_part, cars_out, entered_out, N);
}